// Round 7
// baseline (415.886 us; speedup 1.0000x reference)
//
#include <hip/hip_runtime.h>
#include <hip/hip_cooperative_groups.h>

namespace cg = cooperative_groups;

// GATLayer on MI355X — round 18.
//   r17 post-mortem: wall - sum(kernel dur) ~= 75-80 us across 2 boundaries
//   (~25-30 us each) -- now the largest single cost in the pipeline.
//   r18: ONE cooperative kernel (grid 256 x 512 = 1 block/CU, co-resident),
//   grid.sync() + threadfence between phases. Phase bodies verbatim r17:
//     P: 2 concurrent prep-units/block (separate Ts, shared barriers) +
//        wm->fp16 fold (blocks 0-63) + per-unit qmax -> qpart[512] (no atomic)
//     Y: 2 concurrent sub-blocks x 2 reps = 4 gemm_y tiles/block, XCD-grouped
//     O: gemm_out r17 verbatim, qmv = max of 16 qpart entries
//   LDS = 46080 B union of the three phase layouts.

constexpr int B = 32, C = 512, N = 1024, O = 512;
constexpr float L2E = 1.4426950408889634f;

typedef _Float16 half8 __attribute__((ext_vector_type(8)));
typedef _Float16 half4v __attribute__((ext_vector_type(4)));
typedef _Float16 half2v __attribute__((ext_vector_type(2)));
typedef float f32x4 __attribute__((ext_vector_type(4)));
typedef float f32x16 __attribute__((ext_vector_type(16)));

#if __has_builtin(__builtin_amdgcn_exp2f)
#define EXP2(x) __builtin_amdgcn_exp2f(x)
#else
#define EXP2(x) exp2f(x)
#endif

__device__ __forceinline__ half8 cvt8(float4 a, float4 b) {
  half8 h;
  h[0] = (_Float16)a.x; h[1] = (_Float16)a.y; h[2] = (_Float16)a.z; h[3] = (_Float16)a.w;
  h[4] = (_Float16)b.x; h[5] = (_Float16)b.y; h[6] = (_Float16)b.z; h[7] = (_Float16)b.w;
  return h;
}

// direct global->LDS DMA, 16B per lane; lds dest must be wave-uniform base
__device__ __forceinline__ void gload16(const _Float16* g, _Float16* l) {
  __builtin_amdgcn_global_load_lds(
      (const __attribute__((address_space(1))) unsigned int*)(g),
      (__attribute__((address_space(3))) unsigned int*)(l), 16, 0, 0);
}

__global__ __launch_bounds__(512) void fused_kernel(
    const float* __restrict__ x, const float* __restrict__ wq,
    const float* __restrict__ wk, const float* __restrict__ wm,
    const float* __restrict__ bm, float* __restrict__ q, float* __restrict__ k,
    float* __restrict__ qpart, _Float16* __restrict__ wmh,
    _Float16* __restrict__ xhT, _Float16* __restrict__ Yt,
    float* __restrict__ out) {
  __shared__ __align__(16) unsigned char smem[46080];
  cg::grid_group grid = cg::this_grid();
  int bb = blockIdx.x;
  int t = threadIdx.x;

  // ================= Phase P: prep (2 units) + wm convert =================
  {
    int su = t >> 8, tp = t & 255;
    half2v* Tu = (half2v*)smem + su * (32 * 67);   // 2 x 8576 B
    int unit = bb * 2 + su;                        // 0..511
    int b = unit >> 4, n0 = (unit & 15) * 64;

    if (bb < 64) {  // wm -> fp16: 64 blocks x 4096 floats (512 thr x 8)
      int i = t * 8;
      const float* wsrc = wm + bb * 4096;
      float4 a = *(const float4*)(wsrc + i);
      float4 b4 = *(const float4*)(wsrc + i + 4);
      *(half8*)(wmh + bb * 4096 + i) = cvt8(a, b4);
    }

    int cp = tp >> 3;                 // c-pair 0..31 within 64-c chunk
    int ng = tp & 7;                  // 8 n per thread
    const float* xbase = x + ((size_t)b * C + 2 * cp) * N + n0 + ng * 8;
    int nl = tp >> 2;                 // 0..63: n row for transpose-out
    int hq = tp & 3;                  // 16-half c-quarter
    _Float16* xout = xhT + ((size_t)b * N + n0 + nl) * C + hq * 16;
    float aq[8] = {}, ak[8] = {};

    for (int ch = 0; ch < 8; ++ch) {
      int c0 = ch * 64;
      const float* xr = xbase + (size_t)c0 * N;
      float4 a0 = *(const float4*)(xr);
      float4 a1 = *(const float4*)(xr + 4);
      float4 b0 = *(const float4*)(xr + N);
      float4 b1 = *(const float4*)(xr + N + 4);
      float2 wq2 = *(const float2*)&wq[c0 + 2 * cp];
      float2 wk2 = *(const float2*)&wk[c0 + 2 * cp];
      aq[0] = fmaf(wq2.x, a0.x, fmaf(wq2.y, b0.x, aq[0]));
      aq[1] = fmaf(wq2.x, a0.y, fmaf(wq2.y, b0.y, aq[1]));
      aq[2] = fmaf(wq2.x, a0.z, fmaf(wq2.y, b0.z, aq[2]));
      aq[3] = fmaf(wq2.x, a0.w, fmaf(wq2.y, b0.w, aq[3]));
      aq[4] = fmaf(wq2.x, a1.x, fmaf(wq2.y, b1.x, aq[4]));
      aq[5] = fmaf(wq2.x, a1.y, fmaf(wq2.y, b1.y, aq[5]));
      aq[6] = fmaf(wq2.x, a1.z, fmaf(wq2.y, b1.z, aq[6]));
      aq[7] = fmaf(wq2.x, a1.w, fmaf(wq2.y, b1.w, aq[7]));
      ak[0] = fmaf(wk2.x, a0.x, fmaf(wk2.y, b0.x, ak[0]));
      ak[1] = fmaf(wk2.x, a0.y, fmaf(wk2.y, b0.y, ak[1]));
      ak[2] = fmaf(wk2.x, a0.z, fmaf(wk2.y, b0.z, ak[2]));
      ak[3] = fmaf(wk2.x, a0.w, fmaf(wk2.y, b0.w, ak[3]));
      ak[4] = fmaf(wk2.x, a1.x, fmaf(wk2.y, b1.x, ak[4]));
      ak[5] = fmaf(wk2.x, a1.y, fmaf(wk2.y, b1.y, ak[5]));
      ak[6] = fmaf(wk2.x, a1.z, fmaf(wk2.y, b1.z, ak[6]));
      ak[7] = fmaf(wk2.x, a1.w, fmaf(wk2.y, b1.w, ak[7]));
      {
        half2v* xp = &Tu[cp * 67 + ng * 8];
        xp[0] = half2v{(_Float16)a0.x, (_Float16)b0.x};
        xp[1] = half2v{(_Float16)a0.y, (_Float16)b0.y};
        xp[2] = half2v{(_Float16)a0.z, (_Float16)b0.z};
        xp[3] = half2v{(_Float16)a0.w, (_Float16)b0.w};
        xp[4] = half2v{(_Float16)a1.x, (_Float16)b1.x};
        xp[5] = half2v{(_Float16)a1.y, (_Float16)b1.y};
        xp[6] = half2v{(_Float16)a1.z, (_Float16)b1.z};
        xp[7] = half2v{(_Float16)a1.w, (_Float16)b1.w};
      }
      __syncthreads();
      half8 o0h, o1h;
#pragma unroll
      for (int u = 0; u < 4; ++u) {
        half2v pr = Tu[(hq * 8 + u) * 67 + nl];
        o0h[2 * u] = pr[0]; o0h[2 * u + 1] = pr[1];
      }
#pragma unroll
      for (int u = 4; u < 8; ++u) {
        half2v pr = Tu[(hq * 8 + u) * 67 + nl];
        o1h[2 * (u - 4)] = pr[0]; o1h[2 * (u - 4) + 1] = pr[1];
      }
      *(half8*)(xout + c0)     = o0h;
      *(half8*)(xout + c0 + 8) = o1h;
      __syncthreads();
    }

    // q/k reduction (reuse Tu as float scratch, stride 67)
    float* red = (float*)Tu;
#pragma unroll
    for (int j = 0; j < 8; ++j) red[cp * 67 + ng * 8 + j] = aq[j];
    __syncthreads();
    if (tp < 64) {
      float s = 0.f;
#pragma unroll
      for (int p = 0; p < 32; ++p) s += red[p * 67 + tp];
      float qv = L2E * s;
      q[b * N + n0 + tp] = qv;
      float lm2 = qv;
#pragma unroll
      for (int off = 32; off > 0; off >>= 1)
        lm2 = fmaxf(lm2, __shfl_down(lm2, off, 64));
      if ((t & 63) == 0) qpart[unit] = lm2;   // unit == b*16 + n0/64
    }
    __syncthreads();
#pragma unroll
    for (int j = 0; j < 8; ++j) red[cp * 67 + ng * 8 + j] = ak[j];
    __syncthreads();
    if (tp < 64) {
      float s = 0.f;
#pragma unroll
      for (int p = 0; p < 32; ++p) s += red[p * 67 + tp];
      k[b * N + n0 + tp] = L2E * s;
    }
  }
  __threadfence();
  grid.sync();

  // ================= Phase Y: gemm_y, 4 tiles (2 conc x 2 seq) ============
  {
    int su = t >> 8, tp = t & 255;
    _Float16* Asu = (_Float16*)smem + su * (2 * 128 * 32);  // [2][4096] halfs
    int w = tp >> 6, l = tp & 63;
    int nw = w >> 1, ow = w & 1;
    int lm = l & 15, q8 = (l >> 4) * 8, q4 = (l >> 4) * 4;
    int xcd = bb & 7;

    for (int rep = 0; rep < 2; ++rep) {
      int g = (bb >> 3) * 4 + rep * 2 + su;
      int o_id = g & 3;
      int p2 = xcd * 32 + (g >> 2);
      int n_id = p2 & 7, by = p2 >> 3;
      int n0 = n_id * 128, o0 = o_id * 128;

      const _Float16* asrc[2];
#pragma unroll
      for (int m = 0; m < 2; ++m) {
        int u = m * 256 + tp;              // row = u>>2, col halfs = (u&3)*8
        asrc[m] = xhT + ((size_t)by * N + n0 + (u >> 2)) * C + (u & 3) * 8;
      }
      const _Float16* wb[4];
#pragma unroll
      for (int j = 0; j < 4; ++j)
        wb[j] = wmh + (size_t)(o0 + ow * 64 + j * 16 + lm) * C + q8;

#pragma unroll
      for (int m = 0; m < 2; ++m)
        gload16(asrc[m], &Asu[(m * 256 + (tp & ~63)) * 8]);
      __syncthreads();

      f32x4 acc[4][4] = {};
      for (int it = 0; it < 16; ++it) {
        int p = it & 1;
        if (it < 15) {
          int c1 = (it + 1) * 32;
#pragma unroll
          for (int m = 0; m < 2; ++m)
            gload16(asrc[m] + c1, &Asu[(p ^ 1) * 4096 + (m * 256 + (tp & ~63)) * 8]);
        }
        int c0 = it * 32;
        half8 bf[4];
#pragma unroll
        for (int j = 0; j < 4; ++j) bf[j] = *(const half8*)(wb[j] + c0);
#pragma unroll
        for (int i = 0; i < 4; ++i) {
          half8 af = *(const half8*)&Asu[p * 4096 + (nw * 64 + i * 16 + lm) * 32 + q8];
#pragma unroll
          for (int j = 0; j < 4; ++j)
            acc[i][j] = __builtin_amdgcn_mfma_f32_16x16x32_f16(af, bf[j], acc[i][j], 0, 0, 0);
        }
        __syncthreads();
      }

#pragma unroll
      for (int i = 0; i < 4; ++i) {
        int n_b = n0 + nw * 64 + i * 16 + q4;
#pragma unroll
        for (int j = 0; j < 4; ++j) {
          int o_c = o0 + ow * 64 + j * 16 + lm;
          half4v h;
          h[0] = (_Float16)acc[i][j][0];
          h[1] = (_Float16)acc[i][j][1];
          h[2] = (_Float16)acc[i][j][2];
          h[3] = (_Float16)acc[i][j][3];
          *(half4v*)&Yt[((size_t)by * O + o_c) * N + n_b] = h;
        }
      }
      __syncthreads();  // Asu reuse safe across reps
    }
  }
  __threadfence();
  grid.sync();

  // ================= Phase O: gemm_out (r17 verbatim) =====================
  {
    float* qs = (float*)smem;                          // 4 KB
    _Float16* Ys = (_Float16*)(smem + 4096);           // [2][256*40] 40 KB
    float* izs = (float*)(smem + 4096 + 40960);        // 1 KB
    int xcd = bb & 7, w2 = bb >> 3;
    int pairLocal = w2 >> 2, m_id = w2 & 3;
    int pair = xcd * 8 + pairLocal;
    int o_id = pair & 1, by = pair >> 1;
    int o0 = o_id * 256, m0 = m_id * 256;
    int w = t >> 6, l = t & 63;
    int ml = l & 31, g2 = l >> 5;

    *(float2*)&qs[t * 2] = *(const float2*)&q[by * N + t * 2];
    float qmv = qpart[by * 16];
#pragma unroll
    for (int j = 1; j < 16; ++j) qmv = fmaxf(qmv, qpart[by * 16 + j]);
    float km = k[by * N + m0 + w * 32 + ml];
    float s0 = qmv + km;
    float M  = fmaxf(s0, 0.01f * s0);
    float kc2 = km - M;
    float kc3 = fmaf(0.01f, km, -M);

    half8 ones;
#pragma unroll
    for (int jj = 0; jj < 8; ++jj) ones[jj] = (_Float16)1.0f;
    f32x16 acc_z = {};
    int yr = t >> 1, yp = t & 1;
    const _Float16* ysrc = Yt + ((size_t)by * O + o0 + yr) * N + yp * 16;

    {
      half8 z0 = *(const half8*)(ysrc);
      half8 z1 = *(const half8*)(ysrc + 8);
      *(half8*)&Ys[yr * 40 + yp * 16]     = z0;
      *(half8*)&Ys[yr * 40 + yp * 16 + 8] = z1;
    }
    __syncthreads();  // qs + slab 0

    f32x16 acc[8] = {};
    for (int it = 0; it < N / 32; ++it) {
      int p = it & 1;
      int n0k = it * 32;
      half8 z0, z1;
      if (it < N / 32 - 1) {
        z0 = *(const half8*)(ysrc + n0k + 32);
        z1 = *(const half8*)(ysrc + n0k + 40);
      }
#pragma unroll
      for (int kh = 0; kh < 2; ++kh) {
        float4 qa = *(const float4*)&qs[n0k + kh * 16 + g2 * 8];
        float4 qb = *(const float4*)&qs[n0k + kh * 16 + g2 * 8 + 4];
        float qv[8] = {qa.x, qa.y, qa.z, qa.w, qb.x, qb.y, qb.z, qb.w};
        half8 af;
#pragma unroll
        for (int jj = 0; jj < 8; ++jj) {
          float arg = fmaxf(qv[jj] + kc2, fmaf(0.01f, qv[jj], kc3));
          af[jj] = (_Float16)EXP2(arg);
        }
        acc_z = __builtin_amdgcn_mfma_f32_32x32x16_f16(af, ones, acc_z, 0, 0, 0);
#pragma unroll
        for (int s = 0; s < 8; ++s) {
          half8 bf = *(const half8*)&Ys[p * 10240 + (s * 32 + ml) * 40 + kh * 16 + g2 * 8];
          acc[s] = __builtin_amdgcn_mfma_f32_32x32x16_f16(af, bf, acc[s], 0, 0, 0);
        }
      }
      if (it < N / 32 - 1) {
        *(half8*)&Ys[(p ^ 1) * 10240 + yr * 40 + yp * 16]     = z0;
        *(half8*)&Ys[(p ^ 1) * 10240 + yr * 40 + yp * 16 + 8] = z1;
      }
      __syncthreads();
    }

    if (ml == 0) {
#pragma unroll
      for (int rq = 0; rq < 4; ++rq)
#pragma unroll
        for (int r = 0; r < 4; ++r)
          izs[w * 32 + r + 8 * rq + 4 * g2] = 1.0f / acc_z[rq * 4 + r];
    }
    __syncthreads();

    float4 izv[4];
#pragma unroll
    for (int rq = 0; rq < 4; ++rq)
      izv[rq] = *(const float4*)&izs[w * 32 + 8 * rq + 4 * g2];

#pragma unroll
    for (int s = 0; s < 8; ++s) {
      int o_c = o0 + s * 32 + ml;
      float bias = bm[o_c];
#pragma unroll
      for (int rq = 0; rq < 4; ++rq) {
        int m_b = m0 + w * 32 + 8 * rq + 4 * g2;
        float4 r;
        r.x = fmaxf(fmaf(acc[s][rq * 4 + 0], izv[rq].x, bias), 0.f);
        r.y = fmaxf(fmaf(acc[s][rq * 4 + 1], izv[rq].y, bias), 0.f);
        r.z = fmaxf(fmaf(acc[s][rq * 4 + 2], izv[rq].z, bias), 0.f);
        r.w = fmaxf(fmaf(acc[s][rq * 4 + 3], izv[rq].w, bias), 0.f);
        *(float4*)&out[((size_t)by * O + o_c) * N + m_b] = r;
      }
    }
  }
}

extern "C" void kernel_launch(void* const* d_in, const int* in_sizes, int n_in,
                              void* d_out, int out_size, void* d_ws, size_t ws_size,
                              hipStream_t stream) {
  const float* x  = (const float*)d_in[0];
  const float* wq = (const float*)d_in[1];
  const float* wk = (const float*)d_in[2];
  const float* wm = (const float*)d_in[3];
  const float* bm = (const float*)d_in[4];
  float* out = (float*)d_out;

  // ws: q[B*N] | k[B*N] | qpart[512] | wmh[O*C] f16 | Yt[B*O*N] f16 (~33 MiB)
  float* q     = (float*)d_ws;
  float* k     = q + B * N;
  float* qpart = k + B * N;
  _Float16* wmh = (_Float16*)(qpart + 512);
  _Float16* Yt  = wmh + (size_t)O * C;
  // xhT[b][n][c] fp16 (32 MiB) lives in d_out's first half: fully written in
  // phase P, consumed in phase Y, dead before phase O overwrites out.
  _Float16* xhT = (_Float16*)d_out;

  void* args[] = {(void*)&x, (void*)&wq, (void*)&wk, (void*)&wm, (void*)&bm,
                  (void*)&q, (void*)&k, (void*)&qpart, (void*)&wmh,
                  (void*)&xhT, (void*)&Yt, (void*)&out};
  hipLaunchCooperativeKernel((const void*)fused_kernel, dim3(256), dim3(512),
                             args, 0, stream);
}

// Round 8
// 214.386 us; speedup vs baseline: 1.9399x; 1.9399x over previous
//
#include <hip/hip_runtime.h>

// GATLayer on MI355X — round 19.
//   r18 post-mortem: cooperative fusion REFUTED (311 us fused vs ~130 sum;
//   VALUBusy 5.8% -- phase Y lost 4-blk/CU overlap, grid.sync waits on
//   slowest block, launch gap is fixed harness overhead (~75-105 us), not
//   per-boundary). Revert to r17 3-kernel structure.
//   r19: gemm_out BK 32->64: 16 iters instead of 32 (half the
//   vmcnt(0)+barrier drains, the measured 2-phase stall), 2x latency cover
//   per prefetch, same total LDS traffic, bitwise-identical MFMA sequence.
//   LDS 77 KB (1 block/CU anyway; gfx950 allows >64KB/wg).
//   prep/gemm_y unchanged from r17.

constexpr int B = 32, C = 512, N = 1024, O = 512;
constexpr float L2E = 1.4426950408889634f;

typedef _Float16 half8 __attribute__((ext_vector_type(8)));
typedef _Float16 half4v __attribute__((ext_vector_type(4)));
typedef _Float16 half2v __attribute__((ext_vector_type(2)));
typedef float f32x4 __attribute__((ext_vector_type(4)));
typedef float f32x16 __attribute__((ext_vector_type(16)));

#if __has_builtin(__builtin_amdgcn_exp2f)
#define EXP2(x) __builtin_amdgcn_exp2f(x)
#else
#define EXP2(x) exp2f(x)
#endif

__device__ __forceinline__ half8 cvt8(float4 a, float4 b) {
  half8 h;
  h[0] = (_Float16)a.x; h[1] = (_Float16)a.y; h[2] = (_Float16)a.z; h[3] = (_Float16)a.w;
  h[4] = (_Float16)b.x; h[5] = (_Float16)b.y; h[6] = (_Float16)b.z; h[7] = (_Float16)b.w;
  return h;
}

// direct global->LDS DMA, 16B per lane; lds dest must be wave-uniform base
__device__ __forceinline__ void gload16(const _Float16* g, _Float16* l) {
  __builtin_amdgcn_global_load_lds(
      (const __attribute__((address_space(1))) unsigned int*)(g),
      (__attribute__((address_space(3))) unsigned int*)(l), 16, 0, 0);
}

// ---------------- K0: prep — x -> xhT[b][n][c] fp16 + q,k (L2E-scaled)
//                          + wm -> wmh fp16 (folded, blockIdx.x==0 blocks)
// grid (N/64, B), 256 thr. Each block: 64 n rows, all C, 8 chunks of 64 c.
__global__ __launch_bounds__(256) void prep_kernel(const float* __restrict__ x,
    const float* __restrict__ wq, const float* __restrict__ wk,
    const float* __restrict__ wm,
    float* __restrict__ q, float* __restrict__ k,
    _Float16* __restrict__ wmh, _Float16* __restrict__ xhT) {
  __shared__ half2v Ts[32 * 67];   // 8576 B; reused as float scratch for q/k red
  int b  = blockIdx.y;
  int n0 = blockIdx.x * 64;
  int t = threadIdx.x;

  // folded wm conversion: 32 blocks (x==0), each does a 8192-float slice
  if (blockIdx.x == 0) {
    const float* wsrc = wm + b * 8192;
    _Float16* wdst = wmh + b * 8192;
#pragma unroll
    for (int j = 0; j < 4; ++j) {
      int i = j * 2048 + t * 8;
      float4 a = *(const float4*)(wsrc + i);
      float4 bb = *(const float4*)(wsrc + i + 4);
      *(half8*)(wdst + i) = cvt8(a, bb);
    }
  }

  int cp = t >> 3;                 // c-pair 0..31 within 64-c chunk
  int ng = t & 7;                  // 8 n per thread
  const float* xbase = x + ((size_t)b * C + 2 * cp) * N + n0 + ng * 8;
  int nl = t >> 2;                 // 0..63: n row for transpose-out
  int hq = t & 3;                  // 16-half c-quarter
  _Float16* xout = xhT + ((size_t)b * N + n0 + nl) * C + hq * 16;
  float aq[8] = {}, ak[8] = {};

  for (int ch = 0; ch < 8; ++ch) {
    int c0 = ch * 64;
    const float* xr = xbase + (size_t)c0 * N;
    float4 a0 = *(const float4*)(xr);
    float4 a1 = *(const float4*)(xr + 4);
    float4 b0 = *(const float4*)(xr + N);
    float4 b1 = *(const float4*)(xr + N + 4);
    float2 wq2 = *(const float2*)&wq[c0 + 2 * cp];
    float2 wk2 = *(const float2*)&wk[c0 + 2 * cp];
    aq[0] = fmaf(wq2.x, a0.x, fmaf(wq2.y, b0.x, aq[0]));
    aq[1] = fmaf(wq2.x, a0.y, fmaf(wq2.y, b0.y, aq[1]));
    aq[2] = fmaf(wq2.x, a0.z, fmaf(wq2.y, b0.z, aq[2]));
    aq[3] = fmaf(wq2.x, a0.w, fmaf(wq2.y, b0.w, aq[3]));
    aq[4] = fmaf(wq2.x, a1.x, fmaf(wq2.y, b1.x, aq[4]));
    aq[5] = fmaf(wq2.x, a1.y, fmaf(wq2.y, b1.y, aq[5]));
    aq[6] = fmaf(wq2.x, a1.z, fmaf(wq2.y, b1.z, aq[6]));
    aq[7] = fmaf(wq2.x, a1.w, fmaf(wq2.y, b1.w, aq[7]));
    ak[0] = fmaf(wk2.x, a0.x, fmaf(wk2.y, b0.x, ak[0]));
    ak[1] = fmaf(wk2.x, a0.y, fmaf(wk2.y, b0.y, ak[1]));
    ak[2] = fmaf(wk2.x, a0.z, fmaf(wk2.y, b0.z, ak[2]));
    ak[3] = fmaf(wk2.x, a0.w, fmaf(wk2.y, b0.w, ak[3]));
    ak[4] = fmaf(wk2.x, a1.x, fmaf(wk2.y, b1.x, ak[4]));
    ak[5] = fmaf(wk2.x, a1.y, fmaf(wk2.y, b1.y, ak[5]));
    ak[6] = fmaf(wk2.x, a1.z, fmaf(wk2.y, b1.z, ak[6]));
    ak[7] = fmaf(wk2.x, a1.w, fmaf(wk2.y, b1.w, ak[7]));
    {
      half2v* xp = &Ts[cp * 67 + ng * 8];
      xp[0] = half2v{(_Float16)a0.x, (_Float16)b0.x};
      xp[1] = half2v{(_Float16)a0.y, (_Float16)b0.y};
      xp[2] = half2v{(_Float16)a0.z, (_Float16)b0.z};
      xp[3] = half2v{(_Float16)a0.w, (_Float16)b0.w};
      xp[4] = half2v{(_Float16)a1.x, (_Float16)b1.x};
      xp[5] = half2v{(_Float16)a1.y, (_Float16)b1.y};
      xp[6] = half2v{(_Float16)a1.z, (_Float16)b1.z};
      xp[7] = half2v{(_Float16)a1.w, (_Float16)b1.w};
    }
    __syncthreads();
    // transpose-out: thread -> row nl, c-halfs [hq*16, hq*16+16)
    half8 o0h, o1h;
#pragma unroll
    for (int u = 0; u < 4; ++u) {
      half2v pr = Ts[(hq * 8 + u) * 67 + nl];
      o0h[2 * u] = pr[0]; o0h[2 * u + 1] = pr[1];
    }
#pragma unroll
    for (int u = 4; u < 8; ++u) {
      half2v pr = Ts[(hq * 8 + u) * 67 + nl];
      o1h[2 * (u - 4)] = pr[0]; o1h[2 * (u - 4) + 1] = pr[1];
    }
    *(half8*)(xout + c0)     = o0h;
    *(half8*)(xout + c0 + 8) = o1h;
    __syncthreads();
  }

  // q/k reduction over 32 c-pair groups (reuse Ts as float scratch, stride 67)
  float* red = (float*)Ts;
#pragma unroll
  for (int j = 0; j < 8; ++j) red[cp * 67 + ng * 8 + j] = aq[j];
  __syncthreads();
  if (t < 64) {
    float s = 0.f;
#pragma unroll
    for (int p = 0; p < 32; ++p) s += red[p * 67 + t];
    q[b * N + n0 + t] = L2E * s;
  }
  __syncthreads();
#pragma unroll
  for (int j = 0; j < 8; ++j) red[cp * 67 + ng * 8 + j] = ak[j];
  __syncthreads();
  if (t < 64) {
    float s = 0.f;
#pragma unroll
    for (int p = 0; p < 32; ++p) s += red[p * 67 + t];
    k[b * N + n0 + t] = L2E * s;
  }
}

// ---------------- K1: gemm_y — Yt[b][o][n] = wmh[o,:] . xhT[n,:]  (fp16 MFMA)
// 128n x 128o tile, 256 thr (2x2 waves of 64n x 64o), K=512 in 16 steps of 32.
// A (xhT rows) staged via global_load_lds into dbuf LDS; B (wmh) direct-global.
__global__ __launch_bounds__(256) void gemm_y_kernel(const _Float16* __restrict__ xhT,
    const _Float16* __restrict__ wmh, _Float16* __restrict__ Yt) {
  __shared__ __align__(16) _Float16 As[2][128 * 32];  // 8 KB per buffer
  int f = blockIdx.x;
  int xcd = f & 7, g = f >> 3;
  int o_id = g & 3;                        // fastest within XCD stream
  int p2 = xcd * 32 + (g >> 2);            // 0..255 tile id
  int n_id = p2 & 7, b = p2 >> 3;
  int n0 = n_id * 128, o0 = o_id * 128;
  int t = threadIdx.x;
  int w = t >> 6, l = t & 63;
  int nw = w >> 1, ow = w & 1;
  int lm = l & 15, q8 = (l >> 4) * 8, q4 = (l >> 4) * 4;

  // staging source: instr m covers LDS bytes [m*4096 + w*1024 + lane*16)
  const _Float16* asrc[2];
#pragma unroll
  for (int m = 0; m < 2; ++m) {
    int u = m * 256 + t;                   // row = u>>2, col halfs = (u&3)*8
    asrc[m] = xhT + ((size_t)b * N + n0 + (u >> 2)) * C + (u & 3) * 8;
  }
  const _Float16* wb[4];
#pragma unroll
  for (int j = 0; j < 4; ++j)
    wb[j] = wmh + (size_t)(o0 + ow * 64 + j * 16 + lm) * C + q8;

  // prologue: stage K-step 0 into buf 0
#pragma unroll
  for (int m = 0; m < 2; ++m)
    gload16(asrc[m], &As[0][(m * 256 + (t & ~63)) * 8]);
  __syncthreads();  // compiler drains vmcnt(0) before s_barrier

  f32x4 acc[4][4] = {};
  for (int it = 0; it < 16; ++it) {
    int p = it & 1;
    if (it < 15) {  // stage next K-step; stays in flight across the MFMA block
      int c1 = (it + 1) * 32;
#pragma unroll
      for (int m = 0; m < 2; ++m)
        gload16(asrc[m] + c1, &As[p ^ 1][(m * 256 + (t & ~63)) * 8]);
    }
    int c0 = it * 32;
    half8 bf[4];
#pragma unroll
    for (int j = 0; j < 4; ++j) bf[j] = *(const half8*)(wb[j] + c0);
#pragma unroll
    for (int i = 0; i < 4; ++i) {
      half8 af = *(const half8*)&As[p][(nw * 64 + i * 16 + lm) * 32 + q8];
#pragma unroll
      for (int j = 0; j < 4; ++j)
        acc[i][j] = __builtin_amdgcn_mfma_f32_16x16x32_f16(af, bf[j], acc[i][j], 0, 0, 0);
    }
    __syncthreads();  // single barrier: drains stage(p^1); all reads of p done
  }

#pragma unroll
  for (int i = 0; i < 4; ++i) {
    int n_b = n0 + nw * 64 + i * 16 + q4;
#pragma unroll
    for (int j = 0; j < 4; ++j) {
      int o_c = o0 + ow * 64 + j * 16 + lm;
      half4v h;
      h[0] = (_Float16)acc[i][j][0];
      h[1] = (_Float16)acc[i][j][1];
      h[2] = (_Float16)acc[i][j][2];
      h[3] = (_Float16)acc[i][j][3];
      *(half4v*)&Yt[((size_t)b * O + o_c) * N + n_b] = h;
    }
  }
}

// ---------------- K2: gemm_out — r17 math, BK=64: 16 iters (half the
// vmcnt(0)+barrier drains), dbuf 32KB slabs, bitwise-identical MFMA order.
// 32x32x16 MFMA, block 256o x 256m, 512 thr, qmax in-block.
__global__ __launch_bounds__(512) void gemm_out_kernel(const _Float16* __restrict__ Yt,
    const float* __restrict__ q, const float* __restrict__ k,
    const float* __restrict__ bm, float* __restrict__ out) {
  __shared__ __align__(16) float qs[N];               // 4 KB
  __shared__ __align__(16) _Float16 Ys[2][256 * 72];  // 72 KB (64 data + 8 pad)
  __shared__ float izs[256];
  __shared__ float mred[8];
  int b  = blockIdx.y;
  int o0 = blockIdx.x * 256;
  int m0 = blockIdx.z * 256;
  int t = threadIdx.x;
  int w = t >> 6, l = t & 63;
  int ml = l & 31, g2 = l >> 5;

  float2 q2 = *(const float2*)&q[b * N + t * 2];
  *(float2*)&qs[t * 2] = q2;
  // in-block qmax over the full q row
  float lmax = fmaxf(q2.x, q2.y);
#pragma unroll
  for (int off = 32; off > 0; off >>= 1) lmax = fmaxf(lmax, __shfl_down(lmax, off, 64));
  if (l == 0) mred[w] = lmax;

  float km = k[b * N + m0 + w * 32 + ml];   // issue load pre-barrier

  half8 ones;
#pragma unroll
  for (int jj = 0; jj < 8; ++jj) ones[jj] = (_Float16)1.0f;
  f32x16 acc_z = {};
  // staging: slab = 64 n-halfs/row (128 B); thread (yr,yp) covers halfs
  // [yp*32, yp*32+32) of row yr via 4 half8.
  int yr = t >> 1, yp = t & 1;
  const _Float16* ysrc = Yt + ((size_t)b * O + o0 + yr) * N + yp * 32;
  _Float16* ydst = &Ys[0][yr * 72 + yp * 32];

  // prologue: stage slab 0 (n in [0,64))
  {
    half8 z0 = *(const half8*)(ysrc);
    half8 z1 = *(const half8*)(ysrc + 8);
    half8 z2 = *(const half8*)(ysrc + 16);
    half8 z3 = *(const half8*)(ysrc + 24);
    *(half8*)(ydst)      = z0;
    *(half8*)(ydst + 8)  = z1;
    *(half8*)(ydst + 16) = z2;
    *(half8*)(ydst + 24) = z3;
  }
  __syncthreads();  // qs + mred + slab 0

  float qmv = mred[0];
#pragma unroll
  for (int j = 1; j < 8; ++j) qmv = fmaxf(qmv, mred[j]);
  float s0 = qmv + km;
  float M  = fmaxf(s0, 0.01f * s0);
  float kc2 = km - M;
  float kc3 = fmaf(0.01f, km, -M);

  f32x16 acc[8] = {};
  for (int it = 0; it < N / 64; ++it) {
    int p = it & 1;
    int n0k = it * 64;
    half8 z0, z1, z2, z3;
    if (it < N / 64 - 1) {  // prefetch next slab; drains after the MFMA body
      z0 = *(const half8*)(ysrc + n0k + 64);
      z1 = *(const half8*)(ysrc + n0k + 72);
      z2 = *(const half8*)(ysrc + n0k + 80);
      z3 = *(const half8*)(ysrc + n0k + 88);
    }
#pragma unroll
    for (int kh = 0; kh < 4; ++kh) {
      float4 qa = *(const float4*)&qs[n0k + kh * 16 + g2 * 8];
      float4 qb = *(const float4*)&qs[n0k + kh * 16 + g2 * 8 + 4];
      float qv[8] = {qa.x, qa.y, qa.z, qa.w, qb.x, qb.y, qb.z, qb.w};
      half8 af;
#pragma unroll
      for (int jj = 0; jj < 8; ++jj) {
        float arg = fmaxf(qv[jj] + kc2, fmaf(0.01f, qv[jj], kc3));
        af[jj] = (_Float16)EXP2(arg);
      }
      acc_z = __builtin_amdgcn_mfma_f32_32x32x16_f16(af, ones, acc_z, 0, 0, 0);
#pragma unroll
      for (int s = 0; s < 8; ++s) {
        half8 bf = *(const half8*)&Ys[p][(s * 32 + ml) * 72 + kh * 16 + g2 * 8];
        acc[s] = __builtin_amdgcn_mfma_f32_32x32x16_f16(af, bf, acc[s], 0, 0, 0);
      }
    }
    if (it < N / 64 - 1) {
      _Float16* yd = &Ys[p ^ 1][yr * 72 + yp * 32];
      *(half8*)(yd)      = z0;
      *(half8*)(yd + 8)  = z1;
      *(half8*)(yd + 16) = z2;
      *(half8*)(yd + 24) = z3;
    }
    __syncthreads();  // single barrier: p reads + p^1 writes complete
  }

  // acc_z D: row = (reg&3) + 8*(reg>>2) + 4*g2, col = l&31 (all cols equal)
  if (ml == 0) {
#pragma unroll
    for (int rq = 0; rq < 4; ++rq)
#pragma unroll
      for (int r = 0; r < 4; ++r)
        izs[w * 32 + r + 8 * rq + 4 * g2] = 1.0f / acc_z[rq * 4 + r];
  }
  __syncthreads();

  float4 izv[4];
#pragma unroll
  for (int rq = 0; rq < 4; ++rq)
    izv[rq] = *(const float4*)&izs[w * 32 + 8 * rq + 4 * g2];

  // s outer: per o-row, the rq stores are adjacent (write-combine)
#pragma unroll
  for (int s = 0; s < 8; ++s) {
    int o_c = o0 + s * 32 + ml;
    float bias = bm[o_c];
#pragma unroll
    for (int rq = 0; rq < 4; ++rq) {
      int m_b = m0 + w * 32 + 8 * rq + 4 * g2;
      float4 r;
      r.x = fmaxf(fmaf(acc[s][rq * 4 + 0], izv[rq].x, bias), 0.f);
      r.y = fmaxf(fmaf(acc[s][rq * 4 + 1], izv[rq].y, bias), 0.f);
      r.z = fmaxf(fmaf(acc[s][rq * 4 + 2], izv[rq].z, bias), 0.f);
      r.w = fmaxf(fmaf(acc[s][rq * 4 + 3], izv[rq].w, bias), 0.f);
      *(float4*)&out[((size_t)b * O + o_c) * N + m_b] = r;
    }
  }
}

extern "C" void kernel_launch(void* const* d_in, const int* in_sizes, int n_in,
                              void* d_out, int out_size, void* d_ws, size_t ws_size,
                              hipStream_t stream) {
  const float* x  = (const float*)d_in[0];
  const float* wq = (const float*)d_in[1];
  const float* wk = (const float*)d_in[2];
  const float* wm = (const float*)d_in[3];
  const float* bm = (const float*)d_in[4];
  float* out = (float*)d_out;

  // ws: q[B*N] | k[B*N] | pad | wmh[O*C] f16 | Yt[B*O*N] f16  (~33 MiB)
  float* q    = (float*)d_ws;
  float* k    = q + B * N;
  _Float16* wmh = (_Float16*)(k + B * N + 64);
  _Float16* Yt  = wmh + (size_t)O * C;
  // xhT[b][n][c] fp16 (32 MiB) lives in d_out's first half: fully written by
  // prep, consumed by gemm_y, dead before gemm_out overwrites out.
  _Float16* xhT = (_Float16*)d_out;

  prep_kernel<<<dim3(N / 64, B), 256, 0, stream>>>(x, wq, wk, wm, q, k, wmh, xhT);
  gemm_y_kernel<<<dim3(1024), 256, 0, stream>>>(xhT, wmh, Yt);
  gemm_out_kernel<<<dim3(O / 256, B, N / 256), 512, 0, stream>>>(Yt, q, k, bm, out);
}